// Round 2
// baseline (447.216 us; speedup 1.0000x reference)
//
#include <hip/hip_runtime.h>
#include <math.h>

// Problem constants (match reference setup_inputs)
#define B_    8
#define L_    4096
#define D_    2048
#define D2_   4096      // 2*D
#define T_    128
#define LN_EPS_ 1e-5f

#define NLC    32       // L-chunks for pool (4096/32 = 128 rows per chunk)
#define LCHUNK (L_ / NLC)
#define KC1    64       // k-chunk for gemv1 (red dim D_=2048  -> 32 chunks)
#define NK1    (D_ / KC1)
#define KC2    64       // j-chunk for gemv2 (red dim D2_=4096 -> 64 chunks)
#define NK2    (D2_ / KC2)

// ---------------- K0: per-row mask counts ----------------
__global__ void k_masks(const float* __restrict__ tmask,
                        const float* __restrict__ cmask,
                        float* __restrict__ cnt, float* __restrict__ tcnt) {
  const int b = blockIdx.x;
  const int tid = threadIdx.x;           // 256 threads
  float sc = 0.f, st = 0.f;
  for (int i = tid * 4; i < L_; i += 256 * 4) {
    const float4 c4 = *reinterpret_cast<const float4*>(cmask + b * L_ + i);
    const float4 t4 = *reinterpret_cast<const float4*>(tmask + b * L_ + i);
    sc += c4.x + c4.y + c4.z + c4.w;
    st += t4.x + t4.y + t4.z + t4.w;
  }
  __shared__ float sC[256], sT[256];
  sC[tid] = sc; sT[tid] = st;
  __syncthreads();
  for (int off = 128; off > 0; off >>= 1) {
    if (tid < off) { sC[tid] += sC[tid + off]; sT[tid] += sT[tid + off]; }
    __syncthreads();
  }
  if (tid == 0) { cnt[b] = sC[0]; tcnt[b] = sT[0]; }
}

// ---------------- K1: pool partials (column sum over an L-chunk) -----------
// grid: (NLC, 2, B_), block 256; each thread owns a float4 of d. No atomics:
// each block writes its private partial slice part_pool[lc][b][d].
__global__ void k_pool(const float* __restrict__ x, float* __restrict__ part) {
  const int lc = blockIdx.x;
  const int db = blockIdx.y;
  const int b  = blockIdx.z;
  const int d  = db * 1024 + threadIdx.x * 4;
  const float* p = x + (size_t)b * L_ * D_ + (size_t)lc * LCHUNK * D_ + d;
  float ax = 0.f, ay = 0.f, az = 0.f, aw = 0.f;
  #pragma unroll 16
  for (int l = 0; l < LCHUNK; ++l) {
    const float4 v = *reinterpret_cast<const float4*>(p + (size_t)l * D_);
    ax += v.x; ay += v.y; az += v.z; aw += v.w;
  }
  float4 o = make_float4(ax, ay, az, aw);
  *reinterpret_cast<float4*>(part + ((size_t)lc * B_ + b) * D_ + d) = o;
}

// ---------------- K2: part1[ky][b][j] = ctx_sum_chunk @ W1 -----------------
// grid: (D2_/256 j-blocks, NK1 k-chunks), block 256. Pool reduction folded
// into the LDS staging loads (part_pool is L2-resident). No atomics.
__global__ void k_gemv1(const float* __restrict__ part_pool, // [NLC][B][D]
                        const float* __restrict__ W1,        // [D][2D]
                        float* __restrict__ part1) {         // [NK1][B][2D]
  const int j  = blockIdx.x * 256 + threadIdx.x;
  const int ky = blockIdx.y;
  const int k0 = ky * KC1;
  __shared__ float s[B_][KC1];
  for (int i = threadIdx.x; i < B_ * KC1; i += 256) {
    const int bb = i / KC1, kk = i % KC1;
    float v = 0.f;
    #pragma unroll 8
    for (int lc = 0; lc < NLC; ++lc)
      v += part_pool[((size_t)lc * B_ + bb) * D_ + k0 + kk];
    s[bb][kk] = v;
  }
  __syncthreads();
  float acc[B_];
  #pragma unroll
  for (int bb = 0; bb < B_; ++bb) acc[bb] = 0.f;
  const float* w = W1 + (size_t)k0 * D2_ + j;
  #pragma unroll 4
  for (int k = 0; k < KC1; ++k) {
    const float wv = w[(size_t)k * D2_];
    #pragma unroll
    for (int bb = 0; bb < B_; ++bb) acc[bb] += s[bb][k] * wv;
  }
  #pragma unroll
  for (int bb = 0; bb < B_; ++bb)
    part1[((size_t)ky * B_ + bb) * D2_ + j] = acc[bb];
}

// ---------------- K3: h = GELU(Σ part1 / cnt + b1); hn = LN(h)*g+b ---------
// grid: 8 rows, block 1024 (4 elems/thread as float4)
__global__ void k_gelu_ln(const float* __restrict__ part1,  // [NK1][B][2D]
                          const float* __restrict__ cnt,
                          const float* __restrict__ b1,
                          const float* __restrict__ gamma,
                          const float* __restrict__ beta,
                          float* __restrict__ hn) {
  const int b = blockIdx.x;
  const int tid = threadIdx.x;           // 1024
  const float c = cnt[b];
  const float scale = (c > 0.f) ? (1.f / fmaxf(c, 1.f)) : 0.f;
  const int j = tid * 4;
  float hx = 0.f, hy = 0.f, hz = 0.f, hw = 0.f;
  #pragma unroll 8
  for (int ky = 0; ky < NK1; ++ky) {
    const float4 v = *reinterpret_cast<const float4*>(
        part1 + ((size_t)ky * B_ + b) * D2_ + j);
    hx += v.x; hy += v.y; hz += v.z; hw += v.w;
  }
  const float4 bb = *reinterpret_cast<const float4*>(b1 + j);
  float g[4];
  {
    const float v0 = hx * scale + bb.x;
    const float v1 = hy * scale + bb.y;
    const float v2 = hz * scale + bb.z;
    const float v3 = hw * scale + bb.w;
    g[0] = 0.5f * v0 * (1.f + erff(v0 * 0.70710678118654752f));
    g[1] = 0.5f * v1 * (1.f + erff(v1 * 0.70710678118654752f));
    g[2] = 0.5f * v2 * (1.f + erff(v2 * 0.70710678118654752f));
    g[3] = 0.5f * v3 * (1.f + erff(v3 * 0.70710678118654752f));
  }
  float lsum = g[0] + g[1] + g[2] + g[3];
  float lsq  = g[0]*g[0] + g[1]*g[1] + g[2]*g[2] + g[3]*g[3];
  __shared__ float sS[1024], sQ[1024];
  sS[tid] = lsum; sQ[tid] = lsq;
  __syncthreads();
  for (int off = 512; off > 0; off >>= 1) {
    if (tid < off) { sS[tid] += sS[tid + off]; sQ[tid] += sQ[tid + off]; }
    __syncthreads();
  }
  const float mu  = sS[0] * (1.f / D2_);
  const float var = sQ[0] * (1.f / D2_) - mu * mu;
  const float rs  = rsqrtf(var + LN_EPS_);
  const float4 gm = *reinterpret_cast<const float4*>(gamma + j);
  const float4 bt = *reinterpret_cast<const float4*>(beta + j);
  float4 o;
  o.x = (g[0] - mu) * rs * gm.x + bt.x;
  o.y = (g[1] - mu) * rs * gm.y + bt.y;
  o.z = (g[2] - mu) * rs * gm.z + bt.z;
  o.w = (g[3] - mu) * rs * gm.w + bt.w;
  *reinterpret_cast<float4*>(hn + (size_t)b * D2_ + j) = o;
}

// ---------------- K4: part2[ky][b][d] = hn_chunk @ W2 ----------------------
// grid: (D_/256 d-blocks, NK2 j-chunks), block 256. No atomics.
__global__ void k_gemv2(const float* __restrict__ HN,    // [B][2D]
                        const float* __restrict__ W2,    // [2D][D]
                        float* __restrict__ part2) {     // [NK2][B][D]
  const int d  = blockIdx.x * 256 + threadIdx.x;
  const int ky = blockIdx.y;
  const int j0 = ky * KC2;
  __shared__ float s[B_][KC2];
  for (int i = threadIdx.x; i < B_ * KC2; i += 256) {
    const int bb = i / KC2, jj = i % KC2;
    s[bb][jj] = HN[bb * D2_ + j0 + jj];
  }
  __syncthreads();
  float acc[B_];
  #pragma unroll
  for (int bb = 0; bb < B_; ++bb) acc[bb] = 0.f;
  const float* w = W2 + (size_t)j0 * D_ + d;
  #pragma unroll 4
  for (int k = 0; k < KC2; ++k) {
    const float wv = w[(size_t)k * D_];
    #pragma unroll
    for (int bb = 0; bb < B_; ++bb) acc[bb] += s[bb][k] * wv;
  }
  #pragma unroll
  for (int bb = 0; bb < B_; ++bb)
    part2[((size_t)ky * B_ + bb) * D_ + d] = acc[bb];
}

// ---------------- K5: out_pre[b][d] = Σ_ky part2 + b2[d] -------------------
// grid: 16 blocks × 256 thr, one float4 per thread.
__global__ void k_reduce2(const float* __restrict__ part2,  // [NK2][B][D]
                          const float* __restrict__ b2,
                          float* __restrict__ out_pre) {    // [B][D]
  const int idx = (blockIdx.x * 256 + threadIdx.x) * 4;     // over B*D
  const int b = idx / D_;
  const int d = idx % D_;
  float ax = 0.f, ay = 0.f, az = 0.f, aw = 0.f;
  #pragma unroll 8
  for (int ky = 0; ky < NK2; ++ky) {
    const float4 v = *reinterpret_cast<const float4*>(
        part2 + ((size_t)ky * B_ + b) * D_ + d);
    ax += v.x; ay += v.y; az += v.z; aw += v.w;
  }
  const float4 bv = *reinterpret_cast<const float4*>(b2 + d);
  *reinterpret_cast<float4*>(out_pre + idx) =
      make_float4(ax + bv.x, ay + bv.y, az + bv.z, aw + bv.w);
}

// ---------------- K6: scatter into [B][T][D] with zero padding -------------
__global__ void k_scatter(const float* __restrict__ out_pre,
                          const float* __restrict__ tcnt,
                          float* __restrict__ out) {
  const size_t idx = ((size_t)blockIdx.x * 256 + threadIdx.x) * 4;
  const int d  = (int)(idx % D_);
  const int bt = (int)(idx / D_);
  const int t  = bt % T_;
  const int b  = bt / T_;
  float4 v = make_float4(0.f, 0.f, 0.f, 0.f);
  if (t < (int)(tcnt[b] + 0.5f)) {
    v = *reinterpret_cast<const float4*>(out_pre + b * D_ + d);
  }
  *reinterpret_cast<float4*>(out + idx) = v;
}

extern "C" void kernel_launch(void* const* d_in, const int* in_sizes, int n_in,
                              void* d_out, int out_size, void* d_ws, size_t ws_size,
                              hipStream_t stream) {
  const float* context_repr = (const float*)d_in[0];
  const float* target_mask  = (const float*)d_in[1];
  const float* context_mask = (const float*)d_in[2];
  const float* W1    = (const float*)d_in[3];
  const float* b1    = (const float*)d_in[4];
  const float* gamma = (const float*)d_in[5];
  const float* beta  = (const float*)d_in[6];
  const float* W2    = (const float*)d_in[7];
  const float* b2    = (const float*)d_in[8];
  float* out = (float*)d_out;

  // Workspace layout (floats) — every word is fully written before read;
  // no zero-init, no atomics.
  float* ws        = (float*)d_ws;
  float* part_pool = ws;                               // NLC*B*D   = 524288
  float* cnt       = part_pool + (size_t)NLC * B_ * D_;  // 8
  float* tcnt      = cnt + B_;                           // 8
  float* part1     = tcnt + B_;                          // NK1*B*2D = 1048576
  float* hn        = part1 + (size_t)NK1 * B_ * D2_;     // 8*4096
  float* part2     = hn + (size_t)B_ * D2_;              // NK2*B*D  = 1048576
  float* out_pre   = part2 + (size_t)NK2 * B_ * D_;      // 8*2048

  k_masks<<<dim3(B_), dim3(256), 0, stream>>>(target_mask, context_mask, cnt, tcnt);

  k_pool<<<dim3(NLC, 2, B_), dim3(256), 0, stream>>>(context_repr, part_pool);

  k_gemv1<<<dim3(D2_ / 256, NK1), dim3(256), 0, stream>>>(part_pool, W1, part1);

  k_gelu_ln<<<dim3(B_), dim3(1024), 0, stream>>>(part1, cnt, b1, gamma, beta, hn);

  k_gemv2<<<dim3(D_ / 256, NK2), dim3(256), 0, stream>>>(hn, W2, part2);

  k_reduce2<<<dim3((B_ * D_) / 1024), dim3(256), 0, stream>>>(part2, b2, out_pre);

  const int n_out4 = out_size / 4;             // B*T*D / 4
  k_scatter<<<dim3((n_out4 + 255) / 256), dim3(256), 0, stream>>>(out_pre, tcnt, out);
}